// Round 7
// baseline (1058.866 us; speedup 1.0000x reference)
//
#include <hip/hip_runtime.h>

#define EMB_DIM 32
#define CB_SHIFT 7
#define CB_ROWS 128           // rows per bucket
#define COLBITS 17            // col < 131072 ; (lr<<17)|col fits 24 bits
#define EPB 4096              // edges per partition block
#define P1_T 256
#define SCAN_T 256
#define SCAN_E 8
#define SCAN_BLOCK (SCAN_T * SCAN_E)   // 2048 scan elements per block

// ---------------- bucketed edge-partition build ----------------

// k1: per-(block,bucket) histogram, written block-major (coalesced):
// C[block*ncb + bucket]. The scan reads it transposed.
__global__ void coarse_count(const int* __restrict__ row, int* __restrict__ C,
                             int n_edges, int ncb) {
    __shared__ int h[1024];
    const int t = threadIdx.x;
    for (int idx = t; idx < ncb; idx += P1_T) h[idx] = 0;
    __syncthreads();
    const int base = blockIdx.x * EPB;
    const int end = min(base + EPB, n_edges);
    for (int i = base + t; i < end; i += P1_T)
        atomicAdd(&h[row[i] >> CB_SHIFT], 1);
    __syncthreads();
    for (int idx = t; idx < ncb; idx += P1_T)
        C[(size_t)blockIdx.x * ncb + idx] = h[idx];
}

// ---- hierarchical exclusive scan in bucket-major order ----
// scan position p = bucket*nblk + block ; value = C[block*ncb + bucket].
// Results go to O[p] (bucket-major, coalesced writes).

__global__ void scan_block_sums(const int* __restrict__ C, int* __restrict__ bsum,
                                int M, int ncb, int nblk) {
    const int base = blockIdx.x * SCAN_BLOCK;
    const int t = threadIdx.x;
    int s = 0;
#pragma unroll
    for (int i = 0; i < SCAN_E; ++i) {
        int p = base + i * SCAN_T + t;
        if (p < M) {
            int b = p / nblk;
            int k = p - b * nblk;
            s += C[(size_t)k * ncb + b];
        }
    }
    __shared__ int red[SCAN_T];
    red[t] = s;
    __syncthreads();
    for (int d = SCAN_T / 2; d > 0; d >>= 1) {
        if (t < d) red[t] += red[t + d];
        __syncthreads();
    }
    if (t == 0) bsum[blockIdx.x] = red[0];
}

__global__ void scan_bsum(int* __restrict__ bsum, int nbs) {
    __shared__ int sh[SCAN_T];
    const int t = threadIdx.x;
    int carry = 0;
    for (int base = 0; base < nbs; base += SCAN_T) {
        int v = (base + t < nbs) ? bsum[base + t] : 0;
        sh[t] = v;
        __syncthreads();
        for (int d = 1; d < SCAN_T; d <<= 1) {
            int add = (t >= d) ? sh[t - d] : 0;
            __syncthreads();
            sh[t] += add;
            __syncthreads();
        }
        if (base + t < nbs) bsum[base + t] = carry + sh[t] - v;   // exclusive
        int chunk_total = sh[SCAN_T - 1];
        __syncthreads();
        carry += chunk_total;
    }
}

__global__ void scan_block_write(const int* __restrict__ C, const int* __restrict__ bbase,
                                 int* __restrict__ O, int M, int ncb, int nblk) {
    const int t = threadIdx.x;
    const int lo = blockIdx.x * SCAN_BLOCK + t * SCAN_E;
    int vals[SCAN_E];
#pragma unroll
    for (int i = 0; i < SCAN_E; ++i) {
        int p = lo + i;
        if (p < M) {
            int b = p / nblk;
            int k = p - b * nblk;
            vals[i] = C[(size_t)k * ncb + b];
        } else {
            vals[i] = 0;
        }
    }
    int tsum = 0;
#pragma unroll
    for (int i = 0; i < SCAN_E; ++i) tsum += vals[i];

    __shared__ int sh[SCAN_T];
    sh[t] = tsum;
    __syncthreads();
    for (int d = 1; d < SCAN_T; d <<= 1) {
        int add = (t >= d) ? sh[t - d] : 0;
        __syncthreads();
        sh[t] += add;
        __syncthreads();
    }
    int run = bbase[blockIdx.x] + sh[t] - tsum;
#pragma unroll
    for (int i = 0; i < SCAN_E; ++i) {
        int p = lo + i;
        if (p < M) O[p] = run;
        run += vals[i];
    }
}

// k3: scatter edges into bucket-grouped ebuf. Cursor for (block k, bucket b)
// lives at O[b*nblk + k]; each (block,bucket) run is contiguous.
__global__ void coarse_scatter(const int* __restrict__ row, const int* __restrict__ col,
                               const float* __restrict__ w, const int* __restrict__ O,
                               int2* __restrict__ ebuf, int n_edges, int ncb, int nblk) {
    __shared__ int cur[1024];
    const int t = threadIdx.x;
    for (int idx = t; idx < ncb; idx += P1_T)
        cur[idx] = O[(size_t)idx * nblk + blockIdx.x];
    __syncthreads();
    const int base = blockIdx.x * EPB;
    const int end = min(base + EPB, n_edges);
    for (int i = base + t; i < end; i += P1_T) {
        int r = row[i];
        int pos = atomicAdd(&cur[r >> CB_SHIFT], 1);
        ebuf[pos] = make_int2(((r & (CB_ROWS - 1)) << COLBITS) | col[i], __float_as_int(w[i]));
    }
}

// ---------------- fused edge-parallel SpMV with LDS accumulation ----------------
// One block per 128-row bucket. 8 lanes per edge; lane q gathers float4 quad q
// of X[col] and ds_add's into acc[lr][q*4..]. Row stride 33 floats rotates the
// bank base per row -> LDS-atomic conflicts ~2-way (free). Plain coalesced store.
__global__ void __launch_bounds__(256) spmv_fused(
        const float* __restrict__ X, const int2* __restrict__ ebuf,
        const int* __restrict__ O, float* __restrict__ out,
        int ncb, int nblk, int n_edges, int n_nodes) {
    const int b = blockIdx.x;
    const int base = O[(size_t)b * nblk];
    const int endp = (b + 1 < ncb) ? O[(size_t)(b + 1) * nblk] : n_edges;
    const int t = threadIdx.x;

    __shared__ float acc[CB_ROWS * 33];
    for (int idx = t; idx < CB_ROWS * 33; idx += 256) acc[idx] = 0.f;
    __syncthreads();

    const int g = t >> 3;      // edge slot 0..31
    const int q = t & 7;       // float4 quad within the 32-dim row
    const int qo = q * 4;

    int i = base + g;
    for (; i + 96 < endp; i += 128) {
        int2 e0 = ebuf[i];
        int2 e1 = ebuf[i + 32];
        int2 e2 = ebuf[i + 64];
        int2 e3 = ebuf[i + 96];
        const float4 v0 = *reinterpret_cast<const float4*>(X + (size_t)(e0.x & 0x1FFFF) * EMB_DIM + qo);
        const float4 v1 = *reinterpret_cast<const float4*>(X + (size_t)(e1.x & 0x1FFFF) * EMB_DIM + qo);
        const float4 v2 = *reinterpret_cast<const float4*>(X + (size_t)(e2.x & 0x1FFFF) * EMB_DIM + qo);
        const float4 v3 = *reinterpret_cast<const float4*>(X + (size_t)(e3.x & 0x1FFFF) * EMB_DIM + qo);
        const float w0 = __int_as_float(e0.y), w1 = __int_as_float(e1.y);
        const float w2 = __int_as_float(e2.y), w3 = __int_as_float(e3.y);
        const int a0 = (e0.x >> COLBITS) * 33 + qo;
        const int a1 = (e1.x >> COLBITS) * 33 + qo;
        const int a2 = (e2.x >> COLBITS) * 33 + qo;
        const int a3 = (e3.x >> COLBITS) * 33 + qo;
        atomicAdd(&acc[a0 + 0], w0 * v0.x); atomicAdd(&acc[a0 + 1], w0 * v0.y);
        atomicAdd(&acc[a0 + 2], w0 * v0.z); atomicAdd(&acc[a0 + 3], w0 * v0.w);
        atomicAdd(&acc[a1 + 0], w1 * v1.x); atomicAdd(&acc[a1 + 1], w1 * v1.y);
        atomicAdd(&acc[a1 + 2], w1 * v1.z); atomicAdd(&acc[a1 + 3], w1 * v1.w);
        atomicAdd(&acc[a2 + 0], w2 * v2.x); atomicAdd(&acc[a2 + 1], w2 * v2.y);
        atomicAdd(&acc[a2 + 2], w2 * v2.z); atomicAdd(&acc[a2 + 3], w2 * v2.w);
        atomicAdd(&acc[a3 + 0], w3 * v3.x); atomicAdd(&acc[a3 + 1], w3 * v3.y);
        atomicAdd(&acc[a3 + 2], w3 * v3.z); atomicAdd(&acc[a3 + 3], w3 * v3.w);
    }
    for (; i < endp; i += 32) {
        int2 ev = ebuf[i];
        const float4 v = *reinterpret_cast<const float4*>(X + (size_t)(ev.x & 0x1FFFF) * EMB_DIM + qo);
        const float wt = __int_as_float(ev.y);
        const int a = (ev.x >> COLBITS) * 33 + qo;
        atomicAdd(&acc[a + 0], wt * v.x); atomicAdd(&acc[a + 1], wt * v.y);
        atomicAdd(&acc[a + 2], wt * v.z); atomicAdd(&acc[a + 3], wt * v.w);
    }
    __syncthreads();

    const int rbase = b * CB_ROWS;
    for (int idx = t; idx < CB_ROWS * EMB_DIM; idx += 256) {
        int r = idx >> 5, d = idx & 31;
        int gr = rbase + r;
        if (gr < n_nodes) out[(size_t)gr * EMB_DIM + d] = acc[r * 33 + d];
    }
}

// ---------------- fallback (atomic scatter) ----------------
__global__ void lightgcn_scatter(const float* __restrict__ X, const float* __restrict__ w,
                                 const int* __restrict__ row, const int* __restrict__ col,
                                 float* __restrict__ out, int n_edges) {
    long tid = (long)blockIdx.x * blockDim.x + threadIdx.x;
    int e = (int)(tid >> 3);
    int q = (int)(tid & 7);
    if (e >= n_edges) return;
    const int r = row[e];
    const int c = col[e];
    const float wt = w[e];
    const float4 v = *reinterpret_cast<const float4*>(X + (size_t)c * EMB_DIM + q * 4);
    float* o = out + (size_t)r * EMB_DIM + q * 4;
    atomicAdd(o + 0, wt * v.x);
    atomicAdd(o + 1, wt * v.y);
    atomicAdd(o + 2, wt * v.z);
    atomicAdd(o + 3, wt * v.w);
}

extern "C" void kernel_launch(void* const* d_in, const int* in_sizes, int n_in,
                              void* d_out, int out_size, void* d_ws, size_t ws_size,
                              hipStream_t stream) {
    const float* emb = (const float*)d_in[0];
    const float* w   = (const float*)d_in[1];
    const int*   row = (const int*)d_in[2];
    const int*   col = (const int*)d_in[3];
    // d_in[4] = num_layers (device scalar); fixed at 3 for this problem.

    const int n_nodes = in_sizes[0] / EMB_DIM;
    const int n_edges = in_sizes[1];

    float* out = (float*)d_out;
    const size_t xbytes = (size_t)n_nodes * EMB_DIM * sizeof(float);

    const int ncb  = (n_nodes + CB_ROWS - 1) / CB_ROWS;   // buckets (782)
    const int nblk = (n_edges + EPB - 1) / EPB;           // partition blocks (391)
    const int M    = ncb * nblk;                          // scan length (~306K)
    const int nbs  = (M + SCAN_BLOCK - 1) / SCAN_BLOCK;   // scan blocks (~150)

    // ---- workspace layout: ebuf | tmpX | C | O | bsum ----
    const size_t ebuf_off = 0;
    const size_t ebuf_sz  = ((size_t)n_edges * 8 + 15) & ~(size_t)15;
    const size_t tmpx_off = ebuf_off + ebuf_sz;
    const size_t tmpx_sz  = (xbytes + 15) & ~(size_t)15;
    const size_t C_off    = tmpx_off + tmpx_sz;
    const size_t C_sz     = ((size_t)M * 4 + 15) & ~(size_t)15;
    const size_t O_off    = C_off + C_sz;
    const size_t O_sz     = C_sz;
    const size_t bsum_off = O_off + O_sz;
    const size_t bsum_sz  = ((size_t)(nbs + 1) * 4 + 15) & ~(size_t)15;
    const size_t need     = bsum_off + bsum_sz;

    if (ws_size < need || ncb > 1024) {
        // Fallback: atomic path (needs only xbytes of ws)
        float* tmp = (float*)d_ws;
        const int threads = 256;
        const int blocks = (int)(((long)n_edges * 8 + threads - 1) / threads);
        hipMemsetAsync(d_out, 0, xbytes, stream);
        lightgcn_scatter<<<blocks, threads, 0, stream>>>(emb, w, row, col, out, n_edges);
        hipMemsetAsync(d_ws, 0, xbytes, stream);
        lightgcn_scatter<<<blocks, threads, 0, stream>>>(out, w, row, col, tmp, n_edges);
        hipMemsetAsync(d_out, 0, xbytes, stream);
        lightgcn_scatter<<<blocks, threads, 0, stream>>>(tmp, w, row, col, out, n_edges);
        return;
    }

    char* ws = (char*)d_ws;
    int2*  ebuf = (int2*)(ws + ebuf_off);
    float* tmpX = (float*)(ws + tmpx_off);
    int*   C    = (int*)(ws + C_off);
    int*   O    = (int*)(ws + O_off);
    int*   bsum = (int*)(ws + bsum_off);

    // ---- build bucket-grouped edge list (once; reused for all 3 layers) ----
    coarse_count<<<nblk, P1_T, 0, stream>>>(row, C, n_edges, ncb);
    scan_block_sums<<<nbs, SCAN_T, 0, stream>>>(C, bsum, M, ncb, nblk);
    scan_bsum<<<1, SCAN_T, 0, stream>>>(bsum, nbs);
    scan_block_write<<<nbs, SCAN_T, 0, stream>>>(C, bsum, O, M, ncb, nblk);
    coarse_scatter<<<nblk, P1_T, 0, stream>>>(row, col, w, O, ebuf, n_edges, ncb, nblk);

    // ---- 3 fused layers (edge-parallel, LDS accumulate, no global atomics) ----
    spmv_fused<<<ncb, 256, 0, stream>>>(emb,  ebuf, O, out,  ncb, nblk, n_edges, n_nodes);
    spmv_fused<<<ncb, 256, 0, stream>>>(out,  ebuf, O, tmpX, ncb, nblk, n_edges, n_nodes);
    spmv_fused<<<ncb, 256, 0, stream>>>(tmpX, ebuf, O, out,  ncb, nblk, n_edges, n_nodes);
}

// Round 8
// 172.411 us; speedup vs baseline: 6.1415x; 6.1415x over previous
//
#include <hip/hip_runtime.h>

#define EMB_DIM 32
#define CB_SHIFT 10
#define CB_ROWS 1024          // rows per coarse bucket
#define COLBITS 17            // col < 131072
#define EPB 4096              // edges per partition block
#define P1_T 256
#define SCAN_T 256
#define SCAN_E 8
#define SCAN_BLOCK (SCAN_T * SCAN_E)   // 2048 elements per scan block

// ---------------- radix-partition CSR build ----------------

// k1: per-(block,bucket) histogram, written TRANSPOSED: C[bucket*nblk + block].
__global__ void coarse_count(const int* __restrict__ row, int* __restrict__ C,
                             int n_edges, int ncb, int nblk) {
    __shared__ int h[128];
    const int t = threadIdx.x;
    if (t < 128) h[t] = 0;
    __syncthreads();
    const int base = blockIdx.x * EPB;
    const int end = min(base + EPB, n_edges);
    for (int i = base + t; i < end; i += P1_T)
        atomicAdd(&h[row[i] >> CB_SHIFT], 1);
    __syncthreads();
    if (t < ncb) C[t * nblk + blockIdx.x] = h[t];
}

// ---- hierarchical exclusive scan over C[0..M), in place ----

__global__ void scan_block_sums(const int* __restrict__ C, int* __restrict__ bsum, int M) {
    const int base = blockIdx.x * SCAN_BLOCK;
    const int t = threadIdx.x;
    int s = 0;
#pragma unroll
    for (int i = 0; i < SCAN_E; ++i) {
        int idx = base + i * SCAN_T + t;
        if (idx < M) s += C[idx];
    }
    __shared__ int red[SCAN_T];
    red[t] = s;
    __syncthreads();
    for (int d = SCAN_T / 2; d > 0; d >>= 1) {
        if (t < d) red[t] += red[t + d];
        __syncthreads();
    }
    if (t == 0) bsum[blockIdx.x] = red[0];
}

__global__ void scan_bsum(int* __restrict__ bsum, int nbs, int* __restrict__ off, int n_nodes) {
    __shared__ int sh[SCAN_T];
    const int t = threadIdx.x;
    int carry = 0;
    for (int base = 0; base < nbs; base += SCAN_T) {
        int v = (base + t < nbs) ? bsum[base + t] : 0;
        sh[t] = v;
        __syncthreads();
        for (int d = 1; d < SCAN_T; d <<= 1) {
            int add = (t >= d) ? sh[t - d] : 0;
            __syncthreads();
            sh[t] += add;
            __syncthreads();
        }
        if (base + t < nbs) bsum[base + t] = carry + sh[t] - v;   // exclusive
        int chunk_total = sh[SCAN_T - 1];
        __syncthreads();
        carry += chunk_total;
    }
    if (t == 0) off[n_nodes] = carry;    // total = n_edges
}

__global__ void scan_block_write(int* __restrict__ C, const int* __restrict__ bbase, int M) {
    const int base = blockIdx.x * SCAN_BLOCK;
    const int t = threadIdx.x;
    const int lo = base + t * SCAN_E;
    int vals[SCAN_E];
#pragma unroll
    for (int i = 0; i < SCAN_E; ++i) {
        int idx = lo + i;
        vals[i] = (idx < M) ? C[idx] : 0;
    }
    int tsum = 0;
#pragma unroll
    for (int i = 0; i < SCAN_E; ++i) tsum += vals[i];

    __shared__ int sh[SCAN_T];
    sh[t] = tsum;
    __syncthreads();
    for (int d = 1; d < SCAN_T; d <<= 1) {
        int add = (t >= d) ? sh[t - d] : 0;
        __syncthreads();
        sh[t] += add;
        __syncthreads();
    }
    int run = bbase[blockIdx.x] + sh[t] - tsum;
#pragma unroll
    for (int i = 0; i < SCAN_E; ++i) {
        int idx = lo + i;
        if (idx < M) C[idx] = run;
        run += vals[i];
    }
}

// k3: scatter edges into bucket-grouped ebuf (cursors from transposed C).
__global__ void coarse_scatter(const int* __restrict__ row, const int* __restrict__ col,
                               const float* __restrict__ w, const int* __restrict__ O,
                               int2* __restrict__ ebuf, int n_edges, int ncb, int nblk) {
    __shared__ int cur[128];
    const int t = threadIdx.x;
    if (t < ncb) cur[t] = O[t * nblk + blockIdx.x];
    __syncthreads();
    const int base = blockIdx.x * EPB;
    const int end = min(base + EPB, n_edges);
    for (int i = base + t; i < end; i += P1_T) {
        int r = row[i];
        int pos = atomicAdd(&cur[r >> CB_SHIFT], 1);
        ebuf[pos] = make_int2(((r & (CB_ROWS - 1)) << COLBITS) | col[i], __float_as_int(w[i]));
    }
}

// k4: one block per coarse bucket: LDS 1024-row hist + scan -> off[r];
// permute bucket segment into row-sorted CSR order.
__global__ void fine_localize(const int2* __restrict__ ebuf, const int* __restrict__ O,
                              int ncb, int nblk, int n_edges,
                              int2* __restrict__ colw, int* __restrict__ off, int n_nodes) {
    const int b = blockIdx.x;
    const int base = O[b * nblk];
    const int endp = (b + 1 < ncb) ? O[(b + 1) * nblk] : n_edges;
    const int t = threadIdx.x;

    __shared__ int cnt[CB_ROWS];
    __shared__ int scn[CB_ROWS];
    __shared__ int cur[CB_ROWS];

    cnt[t] = 0;
    __syncthreads();
    for (int i = base + t; i < endp; i += CB_ROWS)
        atomicAdd(&cnt[ebuf[i].x >> COLBITS], 1);
    __syncthreads();

    scn[t] = cnt[t];
    __syncthreads();
    for (int d = 1; d < CB_ROWS; d <<= 1) {
        int add = (t >= d) ? scn[t - d] : 0;
        __syncthreads();
        scn[t] += add;
        __syncthreads();
    }
    const int e0 = scn[t] - cnt[t];
    const int r = b * CB_ROWS + t;
    if (r < n_nodes) off[r] = base + e0;
    cur[t] = e0;
    __syncthreads();

    for (int i = base + t; i < endp; i += CB_ROWS) {
        int2 ev = ebuf[i];
        int lr = ev.x >> COLBITS;
        int pos = base + atomicAdd(&cur[lr], 1);
        colw[pos] = make_int2(ev.x & ((1 << COLBITS) - 1), ev.y);
    }
}

// k5: windowed degree sort. One 1024-thread block per 1024-row window:
// counting-sort rows by (clamped) degree into rord, keeping colw locality.
__global__ void degree_sort(const int* __restrict__ off, int* __restrict__ rord, int n_nodes) {
    const int t = threadIdx.x;                 // 0..1023
    const int base = blockIdx.x * 1024;
    const int r = base + t;
    __shared__ int hist[256];
    __shared__ int cur[256];
    if (t < 256) hist[t] = 0;
    __syncthreads();
    int deg = 0;
    const bool valid = (r < n_nodes);
    if (valid) {
        deg = off[r + 1] - off[r];
        if (deg > 255) deg = 255;
        atomicAdd(&hist[deg], 1);
    }
    __syncthreads();
    for (int d = 1; d < 256; d <<= 1) {
        int add = 0;
        if (t < 256 && t >= d) add = hist[t - d];
        __syncthreads();
        if (t < 256) hist[t] += add;
        __syncthreads();
    }
    if (t < 256) cur[t] = (t > 0) ? hist[t - 1] : 0;   // exclusive
    __syncthreads();
    if (valid) {
        int pos = atomicAdd(&cur[deg], 1);
        rord[base + pos] = r;
    }
}

// ---------------- atomic-free SpMV layer (degree-uniform waves) ----------------
__global__ void spmv_layer(const float* __restrict__ X, const int* __restrict__ off,
                           const int2* __restrict__ colw, const int* __restrict__ rord,
                           float* __restrict__ out, int n_nodes) {
    long tid = (long)blockIdx.x * blockDim.x + threadIdx.x;
    int slot = (int)(tid >> 3);
    int q = (int)(tid & 7);
    if (slot >= n_nodes) return;
    const int r = rord[slot];

    const int start = off[r];
    const int end   = off[r + 1];

    float4 acc = make_float4(0.f, 0.f, 0.f, 0.f);
    int k = start;
    for (; k + 4 <= end; k += 4) {
        int2 cw0 = colw[k + 0];
        int2 cw1 = colw[k + 1];
        int2 cw2 = colw[k + 2];
        int2 cw3 = colw[k + 3];
        const float4 v0 = *reinterpret_cast<const float4*>(X + (size_t)cw0.x * EMB_DIM + q * 4);
        const float4 v1 = *reinterpret_cast<const float4*>(X + (size_t)cw1.x * EMB_DIM + q * 4);
        const float4 v2 = *reinterpret_cast<const float4*>(X + (size_t)cw2.x * EMB_DIM + q * 4);
        const float4 v3 = *reinterpret_cast<const float4*>(X + (size_t)cw3.x * EMB_DIM + q * 4);
        const float w0 = __int_as_float(cw0.y), w1 = __int_as_float(cw1.y);
        const float w2 = __int_as_float(cw2.y), w3 = __int_as_float(cw3.y);
        acc.x += w0 * v0.x; acc.y += w0 * v0.y; acc.z += w0 * v0.z; acc.w += w0 * v0.w;
        acc.x += w1 * v1.x; acc.y += w1 * v1.y; acc.z += w1 * v1.z; acc.w += w1 * v1.w;
        acc.x += w2 * v2.x; acc.y += w2 * v2.y; acc.z += w2 * v2.z; acc.w += w2 * v2.w;
        acc.x += w3 * v3.x; acc.y += w3 * v3.y; acc.z += w3 * v3.z; acc.w += w3 * v3.w;
    }
    for (; k < end; ++k) {
        int2 cw = colw[k];
        const float wt = __int_as_float(cw.y);
        const float4 v = *reinterpret_cast<const float4*>(X + (size_t)cw.x * EMB_DIM + q * 4);
        acc.x += wt * v.x; acc.y += wt * v.y; acc.z += wt * v.z; acc.w += wt * v.w;
    }
    *reinterpret_cast<float4*>(out + (size_t)r * EMB_DIM + q * 4) = acc;
}

// ---------------- fallback (atomic scatter) ----------------
__global__ void lightgcn_scatter(const float* __restrict__ X, const float* __restrict__ w,
                                 const int* __restrict__ row, const int* __restrict__ col,
                                 float* __restrict__ out, int n_edges) {
    long tid = (long)blockIdx.x * blockDim.x + threadIdx.x;
    int e = (int)(tid >> 3);
    int q = (int)(tid & 7);
    if (e >= n_edges) return;
    const int r = row[e];
    const int c = col[e];
    const float wt = w[e];
    const float4 v = *reinterpret_cast<const float4*>(X + (size_t)c * EMB_DIM + q * 4);
    float* o = out + (size_t)r * EMB_DIM + q * 4;
    atomicAdd(o + 0, wt * v.x);
    atomicAdd(o + 1, wt * v.y);
    atomicAdd(o + 2, wt * v.z);
    atomicAdd(o + 3, wt * v.w);
}

extern "C" void kernel_launch(void* const* d_in, const int* in_sizes, int n_in,
                              void* d_out, int out_size, void* d_ws, size_t ws_size,
                              hipStream_t stream) {
    const float* emb = (const float*)d_in[0];
    const float* w   = (const float*)d_in[1];
    const int*   row = (const int*)d_in[2];
    const int*   col = (const int*)d_in[3];
    // d_in[4] = num_layers (device scalar); fixed at 3 for this problem.

    const int n_nodes = in_sizes[0] / EMB_DIM;
    const int n_edges = in_sizes[1];

    float* out = (float*)d_out;
    const size_t xbytes = (size_t)n_nodes * EMB_DIM * sizeof(float);

    const int ncb  = (n_nodes + CB_ROWS - 1) / CB_ROWS;   // coarse buckets (98)
    const int nblk = (n_edges + EPB - 1) / EPB;           // partition blocks (391)
    const int M    = ncb * nblk;                          // scan length (38318)
    const int nbs  = (M + SCAN_BLOCK - 1) / SCAN_BLOCK;   // scan blocks (19)
    const int nwin = (n_nodes + 1023) / 1024;             // degree-sort windows (98)

    // ---- workspace layout ----
    // ebuf (reused as tmpX) | colw | off | C | bsum | rord
    const size_t ebuf_off = 0;
    const size_t ebuf_sz  = (((size_t)n_edges * 8 > xbytes ? (size_t)n_edges * 8 : xbytes) + 15) & ~(size_t)15;
    const size_t colw_off = ebuf_off + ebuf_sz;
    const size_t colw_sz  = ((size_t)n_edges * 8 + 15) & ~(size_t)15;
    const size_t off_off  = colw_off + colw_sz;
    const size_t off_sz   = ((size_t)(n_nodes + 2) * 4 + 15) & ~(size_t)15;
    const size_t C_off    = off_off + off_sz;
    const size_t C_sz     = ((size_t)M * 4 + 15) & ~(size_t)15;
    const size_t bsum_off = C_off + C_sz;
    const size_t bsum_sz  = ((size_t)(nbs + 1) * 4 + 15) & ~(size_t)15;
    const size_t rord_off = bsum_off + bsum_sz;
    const size_t rord_sz  = ((size_t)n_nodes * 4 + 15) & ~(size_t)15;
    const size_t need     = rord_off + rord_sz;

    if (ws_size < need || ncb > 128) {
        // Fallback: atomic path (needs only xbytes of ws)
        float* tmp = (float*)d_ws;
        const int threads = 256;
        const int blocks = (int)(((long)n_edges * 8 + threads - 1) / threads);
        hipMemsetAsync(d_out, 0, xbytes, stream);
        lightgcn_scatter<<<blocks, threads, 0, stream>>>(emb, w, row, col, out, n_edges);
        hipMemsetAsync(d_ws, 0, xbytes, stream);
        lightgcn_scatter<<<blocks, threads, 0, stream>>>(out, w, row, col, tmp, n_edges);
        hipMemsetAsync(d_out, 0, xbytes, stream);
        lightgcn_scatter<<<blocks, threads, 0, stream>>>(tmp, w, row, col, out, n_edges);
        return;
    }

    char* ws = (char*)d_ws;
    int2*  ebuf = (int2*)(ws + ebuf_off);
    float* tmpX = (float*)(ws + ebuf_off);   // alias: ebuf dead after fine_localize
    int2*  colw = (int2*)(ws + colw_off);
    int*   offs = (int*)(ws + off_off);
    int*   C    = (int*)(ws + C_off);
    int*   bsum = (int*)(ws + bsum_off);
    int*   rord = (int*)(ws + rord_off);

    // ---- build CSR + degree-sorted order (once; reused for all 3 layers) ----
    coarse_count<<<nblk, P1_T, 0, stream>>>(row, C, n_edges, ncb, nblk);
    scan_block_sums<<<nbs, SCAN_T, 0, stream>>>(C, bsum, M);
    scan_bsum<<<1, SCAN_T, 0, stream>>>(bsum, nbs, offs, n_nodes);
    scan_block_write<<<nbs, SCAN_T, 0, stream>>>(C, bsum, M);
    coarse_scatter<<<nblk, P1_T, 0, stream>>>(row, col, w, C, ebuf, n_edges, ncb, nblk);
    fine_localize<<<ncb, CB_ROWS, 0, stream>>>(ebuf, C, ncb, nblk, n_edges, colw, offs, n_nodes);
    degree_sort<<<nwin, 1024, 0, stream>>>(offs, rord, n_nodes);

    // ---- 3 atomic-free layers ----
    const int threads = 256;
    const int rblocks = (int)(((long)n_nodes * 8 + threads - 1) / threads);
    spmv_layer<<<rblocks, threads, 0, stream>>>(emb,  offs, colw, rord, out,  n_nodes);
    spmv_layer<<<rblocks, threads, 0, stream>>>(out,  offs, colw, rord, tmpX, n_nodes);
    spmv_layer<<<rblocks, threads, 0, stream>>>(tmpX, offs, colw, rord, out,  n_nodes);
}